// Round 13
// baseline (13531.924 us; speedup 1.0000x reference)
//
#include <hip/hip_runtime.h>

#define T_STEPS 4096
#define N_RES   2048
#define N_IN    64
#define N_OUT   64
#define LEAK    0.3f
#define NOISE_S 0.01f

#define NWG      256     // reservoir WGs (1 per CU)
#define RPW      8       // rows per WG
#define RPWAVE   2       // rows per compute wave
#define NTHREADS 384     // waves 0-3 compute (LDS-only), 4 poll, 5 writer

typedef unsigned int uint32x4 __attribute__((ext_vector_type(4)));

// Raw barrier: LDS visibility only — NO vmcnt drain (the compiler's
// __syncthreads always emits s_waitcnt vmcnt(0) before s_barrier, which
// stalls every wave on its outstanding MALL store acks; that drain has
// been on the critical path in ALL previous rounds).
#define BARRIER_LGKM() asm volatile("s_waitcnt lgkmcnt(0)\ns_barrier" ::: "memory")

// ---------------------------------------------------------------------------
// Kernel 1: it[t][n] = dot(u[t,:], W_in[n,:]) + 0.01*noise[t][n]
// ---------------------------------------------------------------------------
__global__ __launch_bounds__(256) void input_terms_kernel(
    const float* __restrict__ u, const float* __restrict__ noise,
    const float* __restrict__ W_in, float* __restrict__ it) {
  const int t = blockIdx.x;
  const int tid = threadIdx.x;
  __shared__ float su[N_IN];
  if (tid < N_IN) su[tid] = u[(size_t)t * N_IN + tid];
  __syncthreads();
  #pragma unroll
  for (int k = 0; k < N_RES / 256; ++k) {
    const int n = tid + 256 * k;
    const float4* wr = reinterpret_cast<const float4*>(W_in + (size_t)n * N_IN);
    float acc = 0.f;
    #pragma unroll
    for (int j = 0; j < N_IN / 4; ++j) {
      float4 w4 = wr[j];
      acc = fmaf(w4.x, su[4 * j + 0], acc);
      acc = fmaf(w4.y, su[4 * j + 1], acc);
      acc = fmaf(w4.z, su[4 * j + 2], acc);
      acc = fmaf(w4.w, su[4 * j + 3], acc);
    }
    it[(size_t)t * N_RES + n] = acc + NOISE_S * noise[(size_t)t * N_RES + n];
  }
}

// ---------------------------------------------------------------------------
// Kernel 2: persistent recurrence — specialized waves, raw barriers,
// true fire-and-forget stores.
//
// 256 WGs x 384 threads:
//   waves 0-3 (compute): 2 rows each, ALL ops LDS/VALU — they never touch
//     global memory, so their barrier needs only lgkmcnt. After writing
//     their tagged words to the next LDS buffer + stg_raw, lane 0 releases
//     an LDS flag (cnt[wave] = t+1).
//   wave 4 (poller): polls the 510 remote 16B groups of s_{t+1} into the
//     next LDS buffer (b128, conflict-free). Its vmcnt(0) covers only its
//     own poll loads.
//   wave 5 (writer): issues the it[t+1] prefetch at the TOP of the step,
//     spins on the 4 LDS flags (acquire, ~60cy), then fires the WG's 2
//     broadcast dwordx4 stores + it[t] record stores — all fire-and-forget:
//     their acks retire across the raw barrier during the next step.
//
// ONE raw barrier per step. Safety:
//   - compute reads ls[t&1]; poller/compute write ls[(t+1)&1] — disjoint.
//   - ls[(t+1)&1] fills (step t) -> compute reads (t+1): crosses barrier t.
//   - stg_it[(t+1)&1] written step t (writer) -> read step t+1: barrier t.
//   - stg_raw written (compute, step t) -> read (writer, step t): LDS
//     release/acquire flag; next overwrite at t+1 crosses barrier t.
//   - skew <= 2: a WG passes barrier t only after its poller filled ALL of
//     s_{t+1}, which needs every WG's writer to have emitted s_{t+1}, which
//     needs their compute at t, which needed their poll of s_t complete.
//     Mod-4 tags (low 2 mantissa bits, <=3 ulp) disambiguate the skew.
// s_0 = zeros in LDS, never polled.
// ---------------------------------------------------------------------------
__global__ __launch_bounds__(NTHREADS, 1) void reservoir_kernel(
    const float* __restrict__ W, float* __restrict__ it,
    unsigned int* sbuf) {
  const int wg = blockIdx.x;
  const int tid = threadIdx.x;
  const int wave = tid >> 6;       // 0..5
  const int lane = tid & 63;
  const int R = wg * RPW;

  __shared__ float Wl[RPW * N_RES];   // 64 KB
  __shared__ float ls[2][N_RES];      // 16 KB state double buffer
  __shared__ float stg_raw[RPW];      // untagged snew (compute -> writer)
  __shared__ float stg_it[2][RPW];    // staged input terms (writer -> compute)
  __shared__ unsigned int cnt[4];     // compute-wave completion flags

  // ---- prologue (ordinary __syncthreads is fine here, one-time) ----
  {
    const float4* Wg = reinterpret_cast<const float4*>(W + (size_t)R * N_RES);
    float4* Wd = reinterpret_cast<float4*>(Wl);
    for (int idx = tid; idx < RPW * N_RES / 4; idx += NTHREADS)
      Wd[idx] = Wg[idx];
  }
  for (int idx = tid; idx < N_RES; idx += NTHREADS) ls[0][idx] = 0.f;
  if (tid < 4) cnt[tid] = 0;
  if (wave == 5 && lane < RPW) stg_it[0][lane] = it[R + lane];
  __syncthreads();

  if (wave < 4) {
    // ================= compute waves: LDS/VALU only =================
    const int r0 = R + wave * RPWAVE;
    const float4* W0 = reinterpret_cast<const float4*>(Wl + (size_t)(RPWAVE * wave + 0) * N_RES);
    const float4* W1 = reinterpret_cast<const float4*>(Wl + (size_t)(RPWAVE * wave + 1) * N_RES);

    for (unsigned int t = 0; t < T_STEPS; ++t) {
      const float* cur = ls[t & 1];
      float* nxt = ls[(t + 1) & 1];

      const float4* S4 = reinterpret_cast<const float4*>(cur);
      float a0 = 0.f, a1 = 0.f;
      #pragma unroll
      for (int j = 0; j < 8; ++j) {
        const float4 s4 = S4[lane + 64 * j];
        const float4 x0 = W0[lane + 64 * j];
        const float4 x1 = W1[lane + 64 * j];
        a0 = fmaf(x0.x, s4.x, a0); a0 = fmaf(x0.y, s4.y, a0);
        a0 = fmaf(x0.z, s4.z, a0); a0 = fmaf(x0.w, s4.w, a0);
        a1 = fmaf(x1.x, s4.x, a1); a1 = fmaf(x1.y, s4.y, a1);
        a1 = fmaf(x1.z, s4.z, a1); a1 = fmaf(x1.w, s4.w, a1);
      }
      #pragma unroll
      for (int off = 32; off > 0; off >>= 1) {
        a0 += __shfl_xor(a0, off);
        a1 += __shfl_xor(a1, off);
      }

      const unsigned int tg = (t + 1) & 3u;
      if (lane < RPWAVE) {
        const float a = lane ? a1 : a0;
        const float itv = stg_it[t & 1][wave * RPWAVE + lane];
        const float h = tanhf(itv + a);
        const float sold = cur[r0 + lane];
        const float snew = (1.0f - LEAK) * sold + LEAK * h;
        nxt[r0 + lane] = __uint_as_float((__float_as_uint(snew) & ~3u) | tg);
        stg_raw[wave * RPWAVE + lane] = snew;
      }
      // Release flag: writer may emit as soon as all 4 flags hit t+1.
      if (lane == 0)
        __hip_atomic_store(&cnt[wave], t + 1, __ATOMIC_RELEASE,
                           __HIP_MEMORY_SCOPE_WORKGROUP);
      BARRIER_LGKM();
    }
  } else if (wave == 4) {
    // ================= poller: only poll loads, ever =================
    unsigned int ownmask = 0;
    #pragma unroll
    for (int k = 0; k < 8; ++k)
      if (((lane + 64 * k) >> 1) == wg) ownmask |= 1u << k;

    for (unsigned int t = 0; t < T_STEPS; ++t) {
      if (t + 1 < T_STEPS) {
        unsigned int* swb = sbuf + ((t + 1) & 1) * N_RES;
        const unsigned int tg = (t + 1) & 3u;
        const char* p0 = (const char*)swb + lane * 16;
        const char* p1 = p0 + 4096;
        uint32x4* dst = reinterpret_cast<uint32x4*>(ls[(t + 1) & 1]);
        unsigned int need = 0xFFu & ~ownmask;
        for (;;) {
          uint32x4 v0, v1, v2, v3, v4, v5, v6, v7;
          asm volatile(
              "global_load_dwordx4 %0, %8, off sc0 sc1\n\t"
              "global_load_dwordx4 %1, %8, off offset:1024 sc0 sc1\n\t"
              "global_load_dwordx4 %2, %8, off offset:2048 sc0 sc1\n\t"
              "global_load_dwordx4 %3, %8, off offset:3072 sc0 sc1\n\t"
              "global_load_dwordx4 %4, %9, off sc0 sc1\n\t"
              "global_load_dwordx4 %5, %9, off offset:1024 sc0 sc1\n\t"
              "global_load_dwordx4 %6, %9, off offset:2048 sc0 sc1\n\t"
              "global_load_dwordx4 %7, %9, off offset:3072 sc0 sc1\n\t"
              "s_waitcnt vmcnt(0)"
              : "=&v"(v0), "=&v"(v1), "=&v"(v2), "=&v"(v3),
                "=&v"(v4), "=&v"(v5), "=&v"(v6), "=&v"(v7)
              : "v"(p0), "v"(p1)
              : "memory");
          #define CHK(j, Vj)                                                   \
            if ((need & (1u << (j))) &&                                        \
                ((((Vj)[0] ^ tg) | ((Vj)[1] ^ tg) | ((Vj)[2] ^ tg) |           \
                  ((Vj)[3] ^ tg)) & 3u) == 0u) {                               \
              dst[lane + 64 * (j)] = (Vj); need &= ~(1u << (j));               \
            }
          CHK(0, v0) CHK(1, v1) CHK(2, v2) CHK(3, v3)
          CHK(4, v4) CHK(5, v5) CHK(6, v6) CHK(7, v7)
          #undef CHK
          if (__all(need == 0u)) break;
          __builtin_amdgcn_s_sleep(1);
        }
      }
      BARRIER_LGKM();
    }
  } else {
    // ========== writer: all global stores, true fire-and-forget ==========
    for (unsigned int t = 0; t < T_STEPS; ++t) {
      // Prefetch next input terms FIRST (completes during the spin).
      float pf = 0.f;
      if (lane < RPW && t + 1 < T_STEPS)
        pf = it[(size_t)(t + 1) * N_RES + R + lane];

      // Spin on compute flags (LDS acquire, ~60cy granularity).
      {
        bool ready;
        do {
          unsigned int c = t + 1;
          if (lane < 4)
            c = __hip_atomic_load(&cnt[lane], __ATOMIC_ACQUIRE,
                                  __HIP_MEMORY_SCOPE_WORKGROUP);
          ready = __all(c >= t + 1);
        } while (!ready);
      }

      // Stage next input terms to LDS (vmcnt wait here covers only pf,
      // issued before the spin — effectively free).
      if (lane < RPW && t + 1 < T_STEPS) stg_it[(t + 1) & 1][lane] = pf;

      // Broadcast: lanes 0,1 pack one 16B tagged group from LDS, fire it.
      float* nxt = ls[(t + 1) & 1];
      if (lane < 2) {
        const uint32x4 pk =
            *reinterpret_cast<const uint32x4*>(&nxt[R + 4 * lane]);
        unsigned int* dstp = sbuf + ((t + 1) & 1) * N_RES + R + 4 * lane;
        asm volatile("global_store_dwordx4 %0, %1, off sc0 sc1"
                     :: "v"(dstp), "v"(pk) : "memory");
      }
      // Record exact states (fire-and-forget; ack retires next step).
      if (lane < RPW) {
        float rv = stg_raw[lane];
        float* rp = it + (size_t)t * N_RES + R + lane;
        asm volatile("global_store_dword %0, %1, off"
                     :: "v"(rp), "v"(rv) : "memory");
      }
      BARRIER_LGKM();
    }
  }
}

// ---------------------------------------------------------------------------
// Kernel 3: out[t][o] = dot(states[t,:], rw[o,:]) + rb[o]
// ---------------------------------------------------------------------------
__global__ __launch_bounds__(256) void readout_kernel(
    const float* __restrict__ states, const float* __restrict__ rw,
    const float* __restrict__ rb, float* __restrict__ out) {
  const int t = blockIdx.x;
  const int tid = threadIdx.x;
  const int o = tid & 63;
  const int q = tid >> 6;  // 0..3
  __shared__ float ss[N_RES];
  #pragma unroll
  for (int k = 0; k < N_RES / 256; ++k)
    ss[tid + 256 * k] = states[(size_t)t * N_RES + tid + 256 * k];
  __syncthreads();

  const float4* r4 = reinterpret_cast<const float4*>(rw + (size_t)o * N_RES + q * 512);
  float acc = 0.f;
  #pragma unroll 8
  for (int j = 0; j < 128; ++j) {
    float4 w4 = r4[j];
    const int base = q * 512 + 4 * j;
    acc = fmaf(w4.x, ss[base + 0], acc);
    acc = fmaf(w4.y, ss[base + 1], acc);
    acc = fmaf(w4.z, ss[base + 2], acc);
    acc = fmaf(w4.w, ss[base + 3], acc);
  }
  __shared__ float red[256];
  red[tid] = acc;
  __syncthreads();
  if (tid < 64) {
    float v = red[tid] + red[tid + 64] + red[tid + 128] + red[tid + 192];
    out[(size_t)t * N_OUT + tid] = v + rb[tid];
  }
}

// ---------------------------------------------------------------------------
extern "C" void kernel_launch(void* const* d_in, const int* in_sizes, int n_in,
                              void* d_out, int out_size, void* d_ws, size_t ws_size,
                              hipStream_t stream) {
  const float* u     = (const float*)d_in[0];  // [4096, 64]
  const float* noise = (const float*)d_in[1];  // [4096, 2048]
  const float* W_in  = (const float*)d_in[2];  // [2048, 64]
  const float* W     = (const float*)d_in[3];  // [2048, 2048]
  const float* rw    = (const float*)d_in[4];  // [64, 2048]
  const float* rb    = (const float*)d_in[5];  // [64]
  float* out = (float*)d_out;                  // [4096, 64]

  float* it = (float*)d_ws;  // 32 MB: input terms, overwritten with states
  unsigned int* sbuf =
      (unsigned int*)((char*)d_ws + (size_t)T_STEPS * N_RES * sizeof(float));

  // Zero both tagged state buffers every call (0xAA poison would alias tag
  // bits; end-of-run tags must be reset for deterministic replays).
  hipMemsetAsync(sbuf, 0, 2 * N_RES * sizeof(unsigned int), stream);

  input_terms_kernel<<<T_STEPS, 256, 0, stream>>>(u, noise, W_in, it);

  void* args[] = {(void*)&W, (void*)&it, (void*)&sbuf};
  hipLaunchCooperativeKernel((void*)reservoir_kernel, dim3(NWG), dim3(NTHREADS),
                             args, 0, stream);

  readout_kernel<<<T_STEPS, 256, 0, stream>>>(it, rw, rb, out);
}